// Round 4
// 610.392 us; speedup vs baseline: 1.0272x; 1.0272x over previous
//
#include <hip/hip_runtime.h>

// Problem constants (static shapes from setup_inputs / reference)
#define BN   16          // batch
#define TN   60000       // frames
#define FN   80          // features
#define NF4  20          // FN/4 float4 groups
#define SEG  100         // segment / chunk length (frames)
#define NSEG 600         // TN/SEG
#define WIN  600         // CMN_WINDOW
#define SBK  6           // WIN/SEG segments back

// Workspace layout: ck[b][seg][f4][8] floats = {sum.xyzw, sumsq.xyzw}
// RAW per-segment sums (no prefix scan pass).
// size = 16*600*20*8*4 B = 6.144 MB

__global__ __launch_bounds__(256) void k_segsum(const float* __restrict__ x,
                                                float* __restrict__ ck) {
    int tid = blockIdx.x * 256 + threadIdx.x;
    if (tid >= BN * NSEG * NF4) return;
    int f4   = tid % NF4;
    int seg  = (tid / NF4) % NSEG;
    int b    = tid / (NF4 * NSEG);
    const float* p = x + ((size_t)b * TN + (size_t)seg * SEG) * FN + f4 * 4;
    float s0=0.f,s1=0.f,s2=0.f,s3=0.f,q0=0.f,q1=0.f,q2=0.f,q3=0.f;
    for (int i = 0; i < SEG; ++i) {
        float4 v = *reinterpret_cast<const float4*>(p + (size_t)i * FN);
        s0 += v.x; s1 += v.y; s2 += v.z; s3 += v.w;
        q0 += v.x*v.x; q1 += v.y*v.y; q2 += v.z*v.z; q3 += v.w*v.w;
    }
    float* o = ck + (size_t)tid * 8;   // tid ordering (b,seg,f4) == ck layout
    o[0]=s0; o[1]=s1; o[2]=s2; o[3]=s3;
    o[4]=q0; o[5]=q1; o[6]=q2; o[7]=q3;
}

__global__ __launch_bounds__(256) void k_out(const float* __restrict__ x,
                                             const float* __restrict__ ck,
                                             float* __restrict__ out) {
    int tid = blockIdx.x * 256 + threadIdx.x;
    if (tid >= BN * NSEG * NF4) return;
    int f4    = tid % NF4;
    int chunk = (tid / NF4) % NSEG;
    int b     = tid / (NF4 * NSEG);
    size_t base = ((size_t)b * TN + (size_t)chunk * SEG) * FN + f4 * 4;
    const float* xl = x + base;
    float* o = out + base;

    // Gather prefix difference: sum of raw segment records [max(0,chunk-6), chunk).
    // <= 6 loads of 32 B from the 6 MB L2-resident ck buffer.
    float ps0=0.f,ps1=0.f,ps2=0.f,ps3=0.f,pq0=0.f,pq1=0.f,pq2=0.f,pq3=0.f;
    {
        int start = chunk - SBK; if (start < 0) start = 0;
        const float* cp = ck + (((size_t)b * NSEG + start) * NF4 + f4) * 8;
        for (int j = start; j < chunk; ++j) {
            ps0 += cp[0]; ps1 += cp[1]; ps2 += cp[2]; ps3 += cp[3];
            pq0 += cp[4]; pq1 += cp[5]; pq2 += cp[6]; pq3 += cp[7];
            cp += NF4 * 8;
        }
    }

    if (chunk == 0) {
        // t in [0,99]: window fixed [0,100) -> stats = segment 0 raw sums
        const float* c0 = ck + (((size_t)b * NSEG) * NF4 + f4) * 8;
        const float rn = 1.0f / 100.0f;
        float m0=c0[0]*rn, m1=c0[1]*rn, m2=c0[2]*rn, m3=c0[3]*rn;
        float i0=rsqrtf(c0[4]*rn - m0*m0);
        float i1=rsqrtf(c0[5]*rn - m1*m1);
        float i2=rsqrtf(c0[6]*rn - m2*m2);
        float i3=rsqrtf(c0[7]*rn - m3*m3);
        for (int i = 0; i < SEG; ++i) {
            float4 v = *reinterpret_cast<const float4*>(xl + (size_t)i * FN);
            float4 r;
            r.x = (v.x - m0) * i0; r.y = (v.y - m1) * i1;
            r.z = (v.z - m2) * i2; r.w = (v.w - m3) * i3;
            *reinterpret_cast<float4*>(o + (size_t)i * FN) = r;
        }
    } else if (chunk < SBK) {
        // t in [100,599]: window [0, t+1), growing n
        float ls0=ps0, ls1=ps1, ls2=ps2, ls3=ps3;
        float lq0=pq0, lq1=pq1, lq2=pq2, lq3=pq3;
        for (int i = 0; i < SEG; ++i) {
            float4 v = *reinterpret_cast<const float4*>(xl + (size_t)i * FN);
            ls0 += v.x; ls1 += v.y; ls2 += v.z; ls3 += v.w;
            lq0 += v.x*v.x; lq1 += v.y*v.y; lq2 += v.z*v.z; lq3 += v.w*v.w;
            float rn = 1.0f / (float)(chunk * SEG + i + 1);
            float m0=ls0*rn, m1=ls1*rn, m2=ls2*rn, m3=ls3*rn;
            float4 r;
            r.x = (v.x - m0) * rsqrtf(lq0*rn - m0*m0);
            r.y = (v.y - m1) * rsqrtf(lq1*rn - m1*m1);
            r.z = (v.z - m2) * rsqrtf(lq2*rn - m2*m2);
            r.w = (v.w - m3) * rsqrtf(lq3*rn - m3*m3);
            *reinterpret_cast<float4*>(o + (size_t)i * FN) = r;
        }
    } else {
        // t >= 600: window [t-600, t+1), n = 601
        // leading sums start at prefix-difference ps (= prefix[c]-prefix[c-6]);
        // trailing accumulators start at 0 and subtract as we walk chunk c-6.
        float ls0=ps0, ls1=ps1, ls2=ps2, ls3=ps3;
        float lq0=pq0, lq1=pq1, lq2=pq2, lq3=pq3;
        float ts0=0.f, ts1=0.f, ts2=0.f, ts3=0.f;
        float tq0=0.f, tq1=0.f, tq2=0.f, tq3=0.f;
        const float* xt = xl - (size_t)WIN * FN;
        const float rn = 1.0f / 601.0f;
        for (int i = 0; i < SEG; ++i) {
            float4 v = *reinterpret_cast<const float4*>(xl + (size_t)i * FN);
            float4 w = *reinterpret_cast<const float4*>(xt + (size_t)i * FN);
            ls0 += v.x; ls1 += v.y; ls2 += v.z; ls3 += v.w;
            lq0 += v.x*v.x; lq1 += v.y*v.y; lq2 += v.z*v.z; lq3 += v.w*v.w;
            float s0 = ls0 - ts0, s1 = ls1 - ts1, s2 = ls2 - ts2, s3 = ls3 - ts3;
            float q0 = lq0 - tq0, q1 = lq1 - tq1, q2 = lq2 - tq2, q3 = lq3 - tq3;
            float m0 = s0*rn, m1 = s1*rn, m2 = s2*rn, m3 = s3*rn;
            float4 r;
            r.x = (v.x - m0) * rsqrtf(q0*rn - m0*m0);
            r.y = (v.y - m1) * rsqrtf(q1*rn - m1*m1);
            r.z = (v.z - m2) * rsqrtf(q2*rn - m2*m2);
            r.w = (v.w - m3) * rsqrtf(q3*rn - m3*m3);
            *reinterpret_cast<float4*>(o + (size_t)i * FN) = r;
            ts0 += w.x; ts1 += w.y; ts2 += w.z; ts3 += w.w;
            tq0 += w.x*w.x; tq1 += w.y*w.y; tq2 += w.z*w.z; tq3 += w.w*w.w;
        }
    }
}

extern "C" void kernel_launch(void* const* d_in, const int* in_sizes, int n_in,
                              void* d_out, int out_size, void* d_ws, size_t ws_size,
                              hipStream_t stream) {
    const float* x = (const float*)d_in[0];
    float* out = (float*)d_out;
    float* ck = (float*)d_ws;   // needs 6.144 MB

    const int n1 = BN * NSEG * NF4;          // 192000 threads
    k_segsum<<<(n1 + 255) / 256, 256, 0, stream>>>(x, ck);
    k_out<<<(n1 + 255) / 256, 256, 0, stream>>>(x, ck, out);
}